// Round 16
// baseline (40.370 us; speedup 1.0000x reference)
//
#include <hip/hip_runtime.h>

typedef float v4f __attribute__((ext_vector_type(4)));

#define BLK 256
#define SLOTS 8               // i-slots per thread (R5's proven IPT=8)
#define TI (BLK * SLOTS)      // 2048 i's per block
#define TJ 64                 // j's staged per block
#define G_CONST 0.001f
#define EPS_CONST 1e-6f

// R5's exact config (1024 blocks of 256, 4/CU = 16 waves/CU, IPT=8 -> minimal
// LDS/pair) + slot-granular triangle (256x64): slot s active iff i-range ends
// above j0 -> 53% of full pairs. Double-count weights are per-(slot,lane)
// CONSTANTS (w=1/2 iff i's 64-tile start < j's 256-slot end; provably 1 for
// all full slots) folded into mi at init -> hot loop identical to R5.
// Self-pairs masked post-rsq only in has_diag blocks. Model: time ~ K/waves +
// L(LDS/pair); this config sits at the measured optimum of both terms.
__global__ __launch_bounds__(BLK, 4)
void grav_kernel(const float* __restrict__ q, const float* __restrict__ m,
                 float* __restrict__ out, int N) {
  const int b   = blockIdx.z;
  const int tid = threadIdx.x;
  const int i0  = blockIdx.x * TI;
  const int j0  = blockIdx.y * TJ;

  const int d     = j0 - i0;
  const int s_min = d > 0 ? (d >> 8) : 0;
  if (s_min >= SLOTS) return;            // pure upper-triangle block: nothing
  const bool has_diag = (d >= 0);

  __shared__ float xs[TJ], ys[TJ], zs[TJ], sjs[TJ], ms[TJ];
  __shared__ float wsum[4];

  const float* qb = q + (size_t)b * N * 3;

  // Stage j tile: coords, |qj|^2, mass (SoA -> broadcast ds_read_b128).
  if (tid < TJ) {
    const int j = j0 + tid;
    const float x = qb[3 * j + 0];
    const float y = qb[3 * j + 1];
    const float z = qb[3 * j + 2];
    xs[tid]  = x;
    ys[tid]  = y;
    zs[tid]  = z;
    sjs[tid] = fmaf(x, x, fmaf(y, y, z * z));
    ms[tid]  = m[j];
  }

  // Per-slot i-state: -2*coords, |qi|^2+eps, mass*weight, index.
  const int jslot_end = ((j0 >> 8) + 1) << 8;   // end of j's 256-block
  float txi[SLOTS], tyi[SLOTS], tzi[SLOTS], se[SLOTS], mie[SLOTS];
  int   ii[SLOTS];
#pragma unroll
  for (int s = 0; s < SLOTS; ++s) {
    const int i = i0 + s * BLK + tid;
    ii[s] = i;
    const float x = qb[3 * i + 0];
    const float y = qb[3 * i + 1];
    const float z = qb[3 * i + 2];
    txi[s] = -2.f * x;
    tyi[s] = -2.f * y;
    tzi[s] = -2.f * z;
    se[s]  = fmaf(x, x, fmaf(y, y, fmaf(z, z, EPS_CONST)));
    // w = 1/2 iff the transposed pair is also computed somewhere in the grid
    // (i's 64-tile starts below j's 256-slot end); else 1. Constant per lane.
    const float w = ((i & ~63) < jslot_end) ? 0.5f : 1.0f;
    mie[s] = m[i] * w;
  }

  __syncthreads();

  float acc[SLOTS] = {};

  if (has_diag) {
    for (int k = 0; k < TJ; k += 4) {
      const v4f xj = *(const v4f*)&xs[k];
      const v4f yj = *(const v4f*)&ys[k];
      const v4f zj = *(const v4f*)&zs[k];
      const v4f sj = *(const v4f*)&sjs[k];
      const v4f mj = *(const v4f*)&ms[k];
#pragma unroll
      for (int s = 0; s < SLOTS; ++s) {
        if (s < s_min) continue;         // block-uniform scalar skip
#pragma unroll
        for (int u = 0; u < 4; ++u) {
          float t = se[s] + sj[u];
          t = fmaf(txi[s], xj[u], t);
          t = fmaf(tyi[s], yj[u], t);
          t = fmaf(tzi[s], zj[u], t);
          float ri = __builtin_amdgcn_rsqf(t);
          // self pair: t = eps +/- rounding (may be <=0 -> NaN); mask post-rsq
          ri = (ii[s] == j0 + k + u) ? 0.f : ri;
          acc[s] = fmaf(mj[u], ri, acc[s]);
        }
      }
    }
  } else {
    // j-range entirely below all slots: no self pairs, all slots active.
    for (int k = 0; k < TJ; k += 4) {
      const v4f xj = *(const v4f*)&xs[k];
      const v4f yj = *(const v4f*)&ys[k];
      const v4f zj = *(const v4f*)&zs[k];
      const v4f sj = *(const v4f*)&sjs[k];
      const v4f mj = *(const v4f*)&ms[k];
#pragma unroll
      for (int s = 0; s < SLOTS; ++s) {
#pragma unroll
        for (int u = 0; u < 4; ++u) {
          float t = se[s] + sj[u];
          t = fmaf(txi[s], xj[u], t);
          t = fmaf(tyi[s], yj[u], t);
          t = fmaf(tzi[s], zj[u], t);
          acc[s] = fmaf(mj[u], __builtin_amdgcn_rsqf(t), acc[s]);
        }
      }
    }
  }

  float tsum = 0.f;
#pragma unroll
  for (int s = 0; s < SLOTS; ++s) tsum += mie[s] * acc[s];

  // Block reduction: 64-lane shuffle, then across 4 waves via LDS.
#pragma unroll
  for (int off = 32; off > 0; off >>= 1) tsum += __shfl_down(tsum, off);
  const int wid  = tid >> 6;
  const int lane = tid & 63;
  if (lane == 0) wsum[wid] = tsum;
  __syncthreads();
  if (tid == 0) {
    const float s = (wsum[0] + wsum[1]) + (wsum[2] + wsum[3]);
    // weights already encode single/double coverage -> plain -G scale.
    atomicAdd(out + b, s * (-G_CONST));
  }
}

extern "C" void kernel_launch(void* const* d_in, const int* in_sizes, int n_in,
                              void* d_out, int out_size, void* d_ws, size_t ws_size,
                              hipStream_t stream) {
  const float* q = (const float*)d_in[0];
  const float* m = (const float*)d_in[1];
  float* out = (float*)d_out;

  const int N = in_sizes[1];
  const int B = in_sizes[0] / (N * 3);

  hipMemsetAsync(out, 0, (size_t)out_size * sizeof(float), stream);

  dim3 grid(N / TI, N / TJ, B);   // 2 x 64 x 8 = 1024 blocks (25% exit early)
  grav_kernel<<<grid, BLK, 0, stream>>>(q, m, out, N);
}

// Round 17
// 35.504 us; speedup vs baseline: 1.1371x; 1.1371x over previous
//
#include <hip/hip_runtime.h>

typedef float v4f __attribute__((ext_vector_type(4)));

#define BLK 256
#define IPT 8                 // i-particles per thread (lean: 4 regs/slot)
#define TI (BLK * IPT)        // 2048 i's per block
#define TJ 32                 // j's staged per block (small -> many blocks)
#define JBT (TI / TJ)         // 64 j-blocks per i-tile
#define G_CONST 0.001f
#define EPS_CONST 1e-6f

// Occupancy model (fits R5/R14/R15): rate ~ K/(waves/CU) + L*(LDS B/pair).
// This config: IPT=8 (minimal LDS term) + triangle at TI=2048 (75% work) +
// TJ=32 -> 1536 blocks = EXACTLY 6 blocks/CU at bounds(256,6) = 24 waves/CU.
// Lean diff-form (R5's proven loop, 4 regs/slot, no per-pair masking) keeps
// VGPR ~75 < 85 cap. Self-terms: diff-form r2(i,i) == EPS exactly (fma chain
// on identical values) -> subtract mi*rsq(EPS) post-loop, bit-exact (R5).
__global__ __launch_bounds__(BLK, 6)
void grav_kernel(const float* __restrict__ q, const float* __restrict__ m,
                 float* __restrict__ out, int N) {
  const int b   = blockIdx.z;
  const int tid = threadIdx.x;

  // Decode blockIdx.x -> (i-tile a, j-block jt); i-tile a owns JBT*(a+1)
  // j-blocks (nti=2 -> at most 2 iterations).
  int rel = blockIdx.x;
  int a = 0;
  while (rel >= JBT * (a + 1)) { rel -= JBT * (a + 1); ++a; }
  const int jt   = rel;
  const bool diag = (jt >= JBT * a);   // j-tile inside this i-tile's range
  const int i0 = a * TI;
  const int j0 = jt * TJ;

  __shared__ float xs[TJ], ys[TJ], zs[TJ], ms[TJ];
  __shared__ float wsum[4];

  const float* qb = q + (size_t)b * N * 3;

  // Stage j tile: coords + mass (SoA -> broadcast ds_read_b128).
  if (tid < TJ) {
    const int j = j0 + tid;
    xs[tid] = qb[3 * j + 0];
    ys[tid] = qb[3 * j + 1];
    zs[tid] = qb[3 * j + 2];
    ms[tid] = m[j];
  }

  // Per-slot i-state: coords + mass (4 regs x 8 slots).
  float xi[IPT], yi[IPT], zi[IPT], mi[IPT];
#pragma unroll
  for (int s = 0; s < IPT; ++s) {
    const int i = i0 + s * BLK + tid;
    xi[s] = qb[3 * i + 0];
    yi[s] = qb[3 * i + 1];
    zi[s] = qb[3 * i + 2];
    mi[s] = m[i];
  }

  __syncthreads();

  float acc[IPT] = {};

  // Branch-free hot loop, identical for diag/off-diag blocks (R5's proven
  // structure). At i==j: dx=dy=dz=0 -> r2 == EPS exactly -> contribution
  // mi*rsq(EPS), removed bit-exactly after the loop.
  for (int k = 0; k < TJ; k += 4) {
    const v4f xj = *(const v4f*)&xs[k];   // uniform addr -> broadcast read
    const v4f yj = *(const v4f*)&ys[k];
    const v4f zj = *(const v4f*)&zs[k];
    const v4f mj = *(const v4f*)&ms[k];
#pragma unroll
    for (int s = 0; s < IPT; ++s) {
#pragma unroll
      for (int u = 0; u < 4; ++u) {
        const float dx = xi[s] - xj[u];
        const float dy = yi[s] - yj[u];
        const float dz = zi[s] - zj[u];
        const float r2 = fmaf(dx, dx, fmaf(dy, dy, fmaf(dz, dz, EPS_CONST)));
        acc[s] = fmaf(mj[u], __builtin_amdgcn_rsqf(r2), acc[s]);
      }
    }
  }

  float tsum = 0.f;
#pragma unroll
  for (int s = 0; s < IPT; ++s) {
    const int i = i0 + s * BLK + tid;
    float h = acc[s];
    if (diag && i >= j0 && i < j0 + TJ)
      h -= mi[s] * __builtin_amdgcn_rsqf(EPS_CONST);   // bit-exact self removal
    tsum += mi[s] * h;
  }

  // Block reduction: 64-lane shuffle, then across 4 waves via LDS.
#pragma unroll
  for (int off = 32; off > 0; off >>= 1) tsum += __shfl_down(tsum, off);
  const int wid  = tid >> 6;
  const int lane = tid & 63;
  if (lane == 0) wsum[wid] = tsum;
  __syncthreads();
  if (tid == 0) {
    const float s = (wsum[0] + wsum[1]) + (wsum[2] + wsum[3]);
    // off-diag: each unordered pair once -> -G; diag: both orders -> -G/2.
    const float scale = diag ? (-0.5f * G_CONST) : (-G_CONST);
    atomicAdd(out + b, s * scale);
  }
}

extern "C" void kernel_launch(void* const* d_in, const int* in_sizes, int n_in,
                              void* d_out, int out_size, void* d_ws, size_t ws_size,
                              hipStream_t stream) {
  const float* q = (const float*)d_in[0];
  const float* m = (const float*)d_in[1];
  float* out = (float*)d_out;

  const int N = in_sizes[1];
  const int B = in_sizes[0] / (N * 3);

  hipMemsetAsync(out, 0, (size_t)out_size * sizeof(float), stream);

  const int nti = N / TI;                      // 2 i-tiles
  const int bpb = JBT * nti * (nti + 1) / 2;   // 192 blocks per batch
  dim3 grid(bpb, 1, B);                        // 1536 blocks = 6/CU exact
  grav_kernel<<<grid, BLK, 0, stream>>>(q, m, out, N);
}